// Round 9
// baseline (551.232 us; speedup 1.0000x reference)
//
#include <hip/hip_runtime.h>

typedef __attribute__((ext_vector_type(8))) short short8;
typedef __attribute__((ext_vector_type(4))) float f32x4;
typedef unsigned short ushort;
typedef unsigned int uint;

#define DIM 1024
#define NSEQ 1024
#define BATCH 8
#define HEADS 16
#define HD 64
#define HIDDEN 4096
#define NROWS (BATCH * NSEQ)  // 8192

__device__ inline ushort f2bf(float f) {
  uint u = __float_as_uint(f);
  u += 0x7fff + ((u >> 16) & 1);  // round-to-nearest-even
  return (ushort)(u >> 16);
}

__device__ inline f32x4 zero4() {
  f32x4 z; z[0] = 0.f; z[1] = 0.f; z[2] = 0.f; z[3] = 0.f; return z;
}

// gelu(x) = x * sigmoid(2u), u = 0.79788456(x + 0.044715 x^3)  (exact identity
// with the tanh form). exp(-2u) = exp2(-2u*log2e).
__device__ inline float gelu_fast(float x) {
  float u2 = 1.5957691216057308f * (x + 0.044715f * x * x * x);  // 2u
  float e = __builtin_amdgcn_exp2f(-1.4426950408889634f * u2);
  return x / (1.0f + e);
}

#define GLDS16(g, l)                                                  \
  __builtin_amdgcn_global_load_lds(                                   \
      (const __attribute__((address_space(1))) void*)(g),             \
      (__attribute__((address_space(3))) void*)(l), 16, 0, 0)

#define WAITVM(n) asm volatile("s_waitcnt vmcnt(" #n ")" ::: "memory")
#define SBAR() asm volatile("s_barrier" ::: "memory")

// ---------------- LayerNorm (fp32 in -> bf16 out) ----------------
__global__ __launch_bounds__(256) void ln_kernel(
    const float* __restrict__ x, const float* __restrict__ sc,
    const float* __restrict__ bi, ushort* __restrict__ out) {
  int row = blockIdx.x;
  int t = threadIdx.x;
  const float4 v = reinterpret_cast<const float4*>(x + (size_t)row * DIM)[t];
  float s = v.x + v.y + v.z + v.w;
  float s2 = v.x * v.x + v.y * v.y + v.z * v.z + v.w * v.w;
#pragma unroll
  for (int off = 32; off >= 1; off >>= 1) {
    s += __shfl_xor(s, off);
    s2 += __shfl_xor(s2, off);
  }
  __shared__ float ps[4], ps2[4];
  int w = t >> 6;
  if ((t & 63) == 0) { ps[w] = s; ps2[w] = s2; }
  __syncthreads();
  s = ps[0] + ps[1] + ps[2] + ps[3];
  s2 = ps2[0] + ps2[1] + ps2[2] + ps2[3];
  float mu = s * (1.0f / DIM);
  float var = s2 * (1.0f / DIM) - mu * mu;
  float rstd = rsqrtf(var + 1e-6f);
  float4 scv = reinterpret_cast<const float4*>(sc)[t];
  float4 biv = reinterpret_cast<const float4*>(bi)[t];
  ushort4 o;
  o.x = f2bf((v.x - mu) * rstd * scv.x + biv.x);
  o.y = f2bf((v.y - mu) * rstd * scv.y + biv.y);
  o.z = f2bf((v.z - mu) * rstd * scv.z + biv.z);
  o.w = f2bf((v.w - mu) * rstd * scv.w + biv.w);
  reinterpret_cast<ushort4*>(out + (size_t)row * DIM)[t] = o;
}

// ------- fused weight transposes: all four fp32 [K][N] -> bf16 [N][K] -------
__global__ __launch_bounds__(256) void wtrans4_kernel(
    const float* __restrict__ w_qkv, ushort* __restrict__ wqkv_t,
    const float* __restrict__ w_proj, ushort* __restrict__ wproj_t,
    const float* __restrict__ w_fc1, ushort* __restrict__ wfc1_t,
    const float* __restrict__ w_fc2, ushort* __restrict__ wfc2_t) {
  int b = blockIdx.x;
  const float* w; ushort* wt; int K, N, bx, by;
  if (b < 3072) {                    // w_qkv: K=1024, N=3072 (96x32 blocks)
    w = w_qkv; wt = wqkv_t; K = 1024; N = 3072; bx = b % 96; by = b / 96;
  } else if (b < 4096) {             // w_proj: K=1024, N=1024 (32x32)
    int i = b - 3072;
    w = w_proj; wt = wproj_t; K = 1024; N = 1024; bx = i % 32; by = i / 32;
  } else if (b < 8192) {             // w_fc1: K=1024, N=4096 (128x32)
    int i = b - 4096;
    w = w_fc1; wt = wfc1_t; K = 1024; N = 4096; bx = i % 128; by = i / 128;
  } else {                           // w_fc2: K=4096, N=1024 (32x128)
    int i = b - 8192;
    w = w_fc2; wt = wfc2_t; K = 4096; N = 1024; bx = i % 32; by = i / 32;
  }
  __shared__ float tile[32][33];
  int n0 = bx * 32, k0 = by * 32;
  int tx = threadIdx.x & 31, ty = threadIdx.x >> 5;
#pragma unroll
  for (int j = 0; j < 4; j++)
    tile[ty + 8 * j][tx] = w[(size_t)(k0 + ty + 8 * j) * N + n0 + tx];
  __syncthreads();
#pragma unroll
  for (int j = 0; j < 4; j++)
    wt[(size_t)(n0 + ty + 8 * j) * K + k0 + tx] = f2bf(tile[tx][ty + 8 * j]);
}

// ---------------- V transpose: qkv v-part [b,n][h,d] -> vT [b,h,d][n] ----------------
__global__ __launch_bounds__(256) void vtrans_kernel(
    const ushort* __restrict__ qkv, ushort* __restrict__ vT) {
  __shared__ ushort Ts[64 * 64];
  int bh = blockIdx.y;
  int b = bh >> 4, h = bh & 15;
  int n0 = blockIdx.x * 64;
  int t = threadIdx.x;
  const ushort* src = qkv + (size_t)b * NSEQ * 3072 + 2048 + h * 64;
#pragma unroll
  for (int i = 0; i < 2; i++) {
    int ci = i * 256 + t;
    int rr = ci >> 3, c = ci & 7;
    short8 v = *reinterpret_cast<const short8*>(src + (size_t)(n0 + rr) * 3072 + c * 8);
    *reinterpret_cast<short8*>(&Ts[rr * 64 + ((c ^ (rr >> 3)) & 7) * 8]) = v;
  }
  __syncthreads();
  ushort* dst = vT + (size_t)bh * 64 * NSEQ;
#pragma unroll
  for (int i = 0; i < 2; i++) {
    int ci = i * 256 + t;
    int dd = ci >> 3, c = ci & 7;
    short8 v;
#pragma unroll
    for (int j = 0; j < 8; j++) {
      int nn = c * 8 + j;
      v[j] = (short)Ts[nn * 64 + (((dd >> 3) ^ (nn >> 3)) & 7) * 8 + (dd & 7)];
    }
    *reinterpret_cast<short8*>(dst + (size_t)dd * NSEQ + n0 + c * 8) = v;
  }
}

// ---------------- GEMM A: 256-tile pipelined (best for qkv/proj/fc2) --------
// 4-deep LDS circular buffer, BK=32, register prefetch 1 tile ahead,
// ONE vmcnt(L)+s_barrier per K-tile.
template <int BN, int EPI, int KK>
__global__ __launch_bounds__(512, 2) void gemm256_kernel(
    const ushort* __restrict__ A, const ushort* __restrict__ Bt,
    const float* __restrict__ bias, const float* __restrict__ res,
    void* __restrict__ outp, int M, int N) {
  constexpr int BM = 256, BK = 32;
  constexpr int WM = (BN == 256) ? 2 : 4;  // waves in M
  constexpr int WN = 8 / WM;               // waves in N
  constexpr int MR = (BM / WM) / 16;       // 8 or 4 frags per wave in M
  constexpr int NR = (BN / WN) / 16;       // 4 frags per wave in N
  constexpr int AR = 2;                    // A staging rounds (128 rows each)
  constexpr int BR = BN / 128;             // B staging rounds
  constexpr int nkt = KK / BK;             // 32 or 128 (even)
  static_assert(BN == 256 || BN == 128, "");
  static_assert(nkt >= 4 && (nkt % 2) == 0, "");

  __shared__ ushort As[4][BM * BK];        // 64 KB
  __shared__ ushort Bs[4][BN * BK];        // 64/32 KB

  int t = threadIdx.x, lane = t & 63, w = t >> 6;
  int wr = w / WN, wc = w % WN;
  int r = lane & 15, g = lane >> 4;

  // XCD-aware block swizzle (all grids here are multiples of 8 blocks)
  int nwg = gridDim.x * gridDim.y;
  int flat = blockIdx.y * gridDim.x + blockIdx.x;
  int swzf = (flat & 7) * (nwg >> 3) + (flat >> 3);
  int bx = swzf % gridDim.x, by = swzf / gridDim.x;
  int m0 = by * BM, n0 = bx * BN;

  const ushort* Ab = A + (size_t)m0 * KK;
  const ushort* Bb = Bt + (size_t)n0 * KK;

  int srow = t >> 2;                                            // 0..127
  int sgc8 = (((t & 3) ^ (srow & 3) ^ ((srow >> 2) & 3)) & 3) * 8;
  int swb = (w << 4) * BK;                                      // wave LDS base
  int sw = ((g ^ (r & 3) ^ ((r >> 2) & 3)) & 3) * 8;            // read swizzle

  auto stageAB = [&](int kt2) {
    ushort* as = &As[kt2 & 3][0];
    ushort* bs = &Bs[kt2 & 3][0];
    int ko = kt2 * BK;
#pragma unroll
    for (int p = 0; p < AR; p++)
      GLDS16(Ab + (size_t)(p * 128 + srow) * KK + ko + sgc8,
             as + p * 128 * BK + swb);
#pragma unroll
    for (int p = 0; p < BR; p++)
      GLDS16(Bb + (size_t)(p * 128 + srow) * KK + ko + sgc8,
             bs + p * 128 * BK + swb);
  };

  auto ldfrags = [&](int kt2, short8 (&fa_)[MR], short8 (&fb_)[NR]) {
    const ushort* as = &As[kt2 & 3][0];
    const ushort* bs = &Bs[kt2 & 3][0];
#pragma unroll
    for (int mi = 0; mi < MR; mi++)
      fa_[mi] = *reinterpret_cast<const short8*>(
          &as[(wr * (BM / WM) + mi * 16 + r) * BK + sw]);
#pragma unroll
    for (int ni = 0; ni < NR; ni++)
      fb_[ni] = *reinterpret_cast<const short8*>(
          &bs[(wc * (BN / WN) + ni * 16 + r) * BK + sw]);
  };

  f32x4 acc[MR][NR];
#pragma unroll
  for (int mi = 0; mi < MR; mi++)
#pragma unroll
    for (int ni = 0; ni < NR; ni++) acc[mi][ni] = zero4();

  auto body = [&](int kt, short8 (&ca)[MR], short8 (&cb)[NR],
                  short8 (&na)[MR], short8 (&nb)[NR]) {
    if (kt + 1 < nkt) ldfrags(kt + 1, na, nb);   // overlaps MFMAs below
    if (kt + 3 < nkt) stageAB(kt + 3);           // HBM -> buf[kt-1]
    __builtin_amdgcn_s_setprio(1);
#pragma unroll
    for (int mi = 0; mi < MR; mi++)
#pragma unroll
      for (int ni = 0; ni < NR; ni++)
        acc[mi][ni] = __builtin_amdgcn_mfma_f32_16x16x32_bf16(
            ca[mi], cb[ni], acc[mi][ni], 0, 0, 0);
    __builtin_amdgcn_s_setprio(0);
    if (kt + 3 < nkt) {
      if constexpr (BN == 256) WAITVM(4); else WAITVM(3);
      SBAR();
    } else if (kt + 2 < nkt) {
      WAITVM(0);
      SBAR();
    }  // else: last-2 tiles, no future reads/stages -> no sync needed
  };

  // prologue: 3 tiles in flight; wait stage(0),(1) done (stage(2) in flight)
  stageAB(0); stageAB(1); stageAB(2);
  if constexpr (BN == 256) WAITVM(4); else WAITVM(3);
  SBAR();

  short8 fa[2][MR], fb[2][NR];
  ldfrags(0, fa[0], fb[0]);
#pragma unroll 1
  for (int k2 = 0; k2 < nkt / 2; k2++) {
    body(2 * k2 + 0, fa[0], fb[0], fa[1], fb[1]);
    body(2 * k2 + 1, fa[1], fb[1], fa[0], fb[0]);
  }

  int rg = g * 4;
#pragma unroll
  for (int mi = 0; mi < MR; mi++) {
#pragma unroll
    for (int ni = 0; ni < NR; ni++) {
      int row = m0 + wr * (BM / WM) + mi * 16 + rg;
      int col = n0 + wc * (BN / WN) + ni * 16 + r;
      float bv = bias[col];
#pragma unroll
      for (int j = 0; j < 4; j++) {
        float v = acc[mi][ni][j] + bv;
        if (EPI == 1) v = gelu_fast(v);
        if (EPI == 2) {
          reinterpret_cast<float*>(outp)[(size_t)(row + j) * N + col] =
              v + res[(size_t)(row + j) * N + col];
        } else {
          reinterpret_cast<ushort*>(outp)[(size_t)(row + j) * N + col] = f2bf(v);
        }
      }
    }
  }
}

// ---------------- GEMM B: m97 128x128 replica (fc1 113.5 us, R3/R6-exact) ---
// 128x128 tile, BK=32, 256 threads (2x2 waves, 64x64 out each, 4x4 frags),
// 2-deep LDS double-buffer (32 KB), global_load_lds width-16 staging,
// plain __syncthreads per K-tile, __launch_bounds__(256,3). REVERTED from
// R8's 3-deep counted-vmcnt experiment (regressed 113.5->127: VGPR 56->68,
// occ 41->30%, FETCH 74->107MB -- occupancy absorption beats pipelining at
// this geometry, confirmed 3x).
template <int EPI>
__global__ __launch_bounds__(256, 3) void gemm128_kernel(
    const ushort* __restrict__ A, const ushort* __restrict__ Bt,
    const float* __restrict__ bias, const float* __restrict__ res,
    void* __restrict__ outp, int M, int N, int K) {
  constexpr int BM = 128, BN = 128, BK = 32;

  __shared__ ushort As[2][BM * BK];  // 8 KB each
  __shared__ ushort Bs[2][BN * BK];

  int t = threadIdx.x, lane = t & 63, w = t >> 6;
  int wr = w >> 1, wc = w & 1;
  int r = lane & 15, g = lane >> 4;

  // XCD-aware block swizzle (all grids here are multiples of 8 blocks)
  int nwg = gridDim.x * gridDim.y;
  int flat = blockIdx.y * gridDim.x + blockIdx.x;
  int swzf = (flat & 7) * (nwg >> 3) + (flat >> 3);
  int bx = swzf % gridDim.x, by = swzf / gridDim.x;
  int m0 = by * BM, n0 = bx * BN;

  const ushort* Ab = A + (size_t)m0 * K;
  const ushort* Bb = Bt + (size_t)n0 * K;

  int srow = t >> 2;  // 0..63
  int sgc8 = (((t & 3) ^ (srow & 3) ^ ((srow >> 2) & 3)) & 3) * 8;
  int swb = (t >> 6) * 16 * BK;  // wave LDS base (rows w*16.., 1 KB per wave)
  int sw = ((g ^ (r & 3) ^ ((r >> 2) & 3)) & 3) * 8;  // read-side swizzle

  f32x4 acc[4][4];
#pragma unroll
  for (int mi = 0; mi < 4; mi++)
#pragma unroll
    for (int ni = 0; ni < 4; ni++) acc[mi][ni] = zero4();

  int nkt = K / BK;
  // prologue: stage tile 0 into buf 0
#pragma unroll
  for (int p = 0; p < 2; p++) {
    GLDS16(Ab + (size_t)(p * 64 + srow) * K + sgc8, &As[0][(p * 64) * BK + swb]);
    GLDS16(Bb + (size_t)(p * 64 + srow) * K + sgc8, &Bs[0][(p * 64) * BK + swb]);
  }
  __syncthreads();

  int cur = 0;
  for (int kt = 0; kt < nkt; kt++) {
    if (kt + 1 < nkt) {  // stage next tile; drained by the __syncthreads below
      int ko = (kt + 1) * BK;
#pragma unroll
      for (int p = 0; p < 2; p++) {
        GLDS16(Ab + (size_t)(p * 64 + srow) * K + ko + sgc8,
               &As[cur ^ 1][(p * 64) * BK + swb]);
        GLDS16(Bb + (size_t)(p * 64 + srow) * K + ko + sgc8,
               &Bs[cur ^ 1][(p * 64) * BK + swb]);
      }
    }
    short8 a[4], b[4];
#pragma unroll
    for (int mi = 0; mi < 4; mi++)
      a[mi] = *reinterpret_cast<const short8*>(
          &As[cur][(wr * 64 + mi * 16 + r) * BK + sw]);
#pragma unroll
    for (int ni = 0; ni < 4; ni++)
      b[ni] = *reinterpret_cast<const short8*>(
          &Bs[cur][(wc * 64 + ni * 16 + r) * BK + sw]);
#pragma unroll
    for (int mi = 0; mi < 4; mi++)
#pragma unroll
      for (int ni = 0; ni < 4; ni++)
        acc[mi][ni] = __builtin_amdgcn_mfma_f32_16x16x32_bf16(
            a[mi], b[ni], acc[mi][ni], 0, 0, 0);
    __syncthreads();  // drains GLDS (vmcnt 0) + all waves done with buf[cur]
    cur ^= 1;
  }

  int rg = g * 4;
#pragma unroll
  for (int mi = 0; mi < 4; mi++) {
#pragma unroll
    for (int ni = 0; ni < 4; ni++) {
      int row = m0 + wr * 64 + mi * 16 + rg;
      int col = n0 + wc * 64 + ni * 16 + r;
      float bv = bias[col];
#pragma unroll
      for (int j = 0; j < 4; j++) {
        float v = acc[mi][ni][j] + bv;
        if (EPI == 1) v = gelu_fast(v);
        if (EPI == 2) {
          reinterpret_cast<float*>(outp)[(size_t)(row + j) * N + col] =
              v + res[(size_t)(row + j) * N + col];
        } else {
          reinterpret_cast<ushort*>(outp)[(size_t)(row + j) * N + col] = f2bf(v);
        }
      }
    }
  }
}

// ---------------- flash attention (no-max-subtract softmax) ----------------
// CHANGED: K/V LDS staging + 2 barriers/tile REMOVED (Common-mistake #7 /
// m169: at S=1024 the 256 KB K/V per (b,h) is L2-resident -- reused by 16
// q-blocks -- and staging is pure overhead; dropping it measured +26%).
// K fragments read directly from qkv (64B/row consumed), V from vT (64B/row).
// Kernel is now barrier-free (Pl is wave-private); LDS 27.6->9.2 KB lets ~8
// blocks/CU co-reside. setprio(1) around MFMA clusters: waves now run at
// independent phases -> the m191 attn regime where setprio measured +4-7%.
#define SM_SCALE_L2E 0.18033688f   // 0.125 * log2(e)
#define SM_BIAS_L2E 11.54156036f   // 8 * log2(e)
__global__ __launch_bounds__(256) void attn_kernel(
    const ushort* __restrict__ qkv, const ushort* __restrict__ vT,
    ushort* __restrict__ o) {
  __shared__ ushort Pl[4][16 * 72];
  int q0 = blockIdx.x * 64, h = blockIdx.y, b = blockIdx.z;
  int t = threadIdx.x, lane = t & 63, w = t >> 6;
  int r = lane & 15, g = lane >> 4;
  const ushort* base = qkv + (size_t)b * NSEQ * 3072 + h * 64;
  const ushort* kbase = base + 1024;
  const ushort* vbase = vT + (size_t)(b * HEADS + h) * 64 * NSEQ;

  short8 qf[2];
  {
    const ushort* qrow = base + (size_t)(q0 + w * 16 + r) * 3072;
    qf[0] = *reinterpret_cast<const short8*>(qrow + g * 8);
    qf[1] = *reinterpret_cast<const short8*>(qrow + 32 + g * 8);
  }

  float l[4] = {0.f, 0.f, 0.f, 0.f};
  f32x4 oacc[4];
#pragma unroll
  for (int db = 0; db < 4; db++) oacc[db] = zero4();

  for (int kt = 0; kt < NSEQ / 64; kt++) {
    int k0 = kt * 64;
    // ---- QK^T + softmax-weight, direct K reads (L2-resident) ----
#pragma unroll
    for (int kb = 0; kb < 4; kb++) {
      const ushort* krow = kbase + (size_t)(k0 + kb * 16 + r) * 3072 + g * 8;
      short8 kf0 = *reinterpret_cast<const short8*>(krow);
      short8 kf1 = *reinterpret_cast<const short8*>(krow + 32);
      f32x4 z = zero4();
      __builtin_amdgcn_s_setprio(1);
      z = __builtin_amdgcn_mfma_f32_16x16x32_bf16(qf[0], kf0, z, 0, 0, 0);
      z = __builtin_amdgcn_mfma_f32_16x16x32_bf16(qf[1], kf1, z, 0, 0, 0);
      __builtin_amdgcn_s_setprio(0);
#pragma unroll
      for (int j = 0; j < 4; j++) {
        float p = __builtin_amdgcn_exp2f(fmaf(z[j], SM_SCALE_L2E, -SM_BIAS_L2E));
        l[j] += p;
        Pl[w][(g * 4 + j) * 72 + kb * 16 + r] = (ushort)(__float_as_uint(p) >> 16);
      }
    }

    // ---- PV, direct V reads from vT (L2-resident) ----
#pragma unroll
    for (int ks = 0; ks < 2; ks++) {
      short8 pa = *reinterpret_cast<const short8*>(&Pl[w][r * 72 + ks * 32 + g * 8]);
      __builtin_amdgcn_s_setprio(1);
#pragma unroll
      for (int db = 0; db < 4; db++) {
        short8 vb = *reinterpret_cast<const short8*>(
            vbase + (size_t)(db * 16 + r) * NSEQ + k0 + ks * 32 + g * 8);
        oacc[db] = __builtin_amdgcn_mfma_f32_16x16x32_bf16(pa, vb, oacc[db], 0, 0, 0);
      }
      __builtin_amdgcn_s_setprio(0);
    }
  }

#pragma unroll
  for (int j = 0; j < 4; j++) {
#pragma unroll
    for (int off = 8; off >= 1; off >>= 1) l[j] += __shfl_xor(l[j], off);
    l[j] = 1.0f / l[j];
  }

#pragma unroll
  for (int db = 0; db < 4; db++)
#pragma unroll
    for (int j = 0; j < 4; j++) {
      size_t row = (size_t)b * NSEQ + q0 + w * 16 + g * 4 + j;
      int col = h * 64 + db * 16 + r;
      o[row * DIM + col] = f2bf(oacc[db][j] * l[j]);
    }
}

// ---------------- driver ----------------
extern "C" void kernel_launch(void* const* d_in, const int* in_sizes, int n_in,
                              void* d_out, int out_size, void* d_ws, size_t ws_size,
                              hipStream_t stream) {
  const float* x      = (const float*)d_in[0];
  const float* w_qkv  = (const float*)d_in[1];
  const float* b_qkv  = (const float*)d_in[2];
  const float* w_proj = (const float*)d_in[3];
  const float* b_proj = (const float*)d_in[4];
  const float* ln1s   = (const float*)d_in[5];
  const float* ln1b   = (const float*)d_in[6];
  const float* ln2s   = (const float*)d_in[7];
  const float* ln2b   = (const float*)d_in[8];
  const float* w_fc1  = (const float*)d_in[9];
  const float* b_fc1  = (const float*)d_in[10];
  const float* w_fc2  = (const float*)d_in[11];
  const float* b_fc2  = (const float*)d_in[12];
  float* out = (float*)d_out;

  char* ws = (char*)d_ws;
  ushort* wqkv_t  = (ushort*)(ws);               // [3072][1024] bf16, 6 MB
  ushort* wproj_t = (ushort*)(ws + 6291456);     // [1024][1024], 2 MB
  ushort* wfc1_t  = (ushort*)(ws + 8388608);     // [4096][1024], 8 MB
  ushort* wfc2_t  = (ushort*)(ws + 16777216);    // [1024][4096], 8 MB
  ushort* hbuf    = (ushort*)(ws + 25165824);    // [8192][1024] bf16, 16 MB
  float*  x1      = (float*)(ws + 41943040);     // [8192][1024] f32, 32 MB
  ushort* vTb     = (ushort*)(ws + 41943040);    // [128][64][1024] bf16, 16 MB (dead before x1)
  ushort* qkv     = (ushort*)(ws + 75497472);    // [8192][3072] bf16, 48 MB
  ushort* obuf    = (ushort*)(ws + 125829120);   // [8192][1024] bf16, 16 MB
  ushort* fc1a    = qkv;                         // [8192][4096] bf16, 64 MB

  wtrans4_kernel<<<12288, 256, 0, stream>>>(
      w_qkv, wqkv_t, w_proj, wproj_t, w_fc1, wfc1_t, w_fc2, wfc2_t);

  // attention branch
  ln_kernel<<<NROWS, 256, 0, stream>>>(x, ln1s, ln1b, hbuf);
  gemm256_kernel<128, 0, 1024><<<dim3(3072 / 128, NROWS / 256), 512, 0, stream>>>(
      hbuf, wqkv_t, b_qkv, nullptr, qkv, NROWS, 3072);
  vtrans_kernel<<<dim3(NSEQ / 64, BATCH * HEADS), 256, 0, stream>>>(qkv, vTb);
  attn_kernel<<<dim3(NSEQ / 64, HEADS, BATCH), 256, 0, stream>>>(qkv, vTb, obuf);
  gemm256_kernel<128, 2, 1024><<<dim3(1024 / 128, NROWS / 256), 512, 0, stream>>>(
      obuf, wproj_t, b_proj, x, x1, NROWS, 1024);

  // mlp branch
  ln_kernel<<<NROWS, 256, 0, stream>>>(x1, ln2s, ln2b, hbuf);
  gemm128_kernel<1><<<dim3(4096 / 128, NROWS / 128), 256, 0, stream>>>(
      hbuf, wfc1_t, b_fc1, nullptr, fc1a, NROWS, 4096, 1024);
  gemm256_kernel<128, 2, 4096><<<dim3(1024 / 128, NROWS / 256), 512, 0, stream>>>(
      fc1a, wfc2_t, b_fc2, x1, out, NROWS, 1024);
}

// Round 10
// 391.434 us; speedup vs baseline: 1.4082x; 1.4082x over previous
//
#include <hip/hip_runtime.h>

typedef __attribute__((ext_vector_type(8))) short short8;
typedef __attribute__((ext_vector_type(4))) float f32x4;
typedef unsigned short ushort;
typedef unsigned int uint;

#define DIM 1024
#define NSEQ 1024
#define BATCH 8
#define HEADS 16
#define HD 64
#define HIDDEN 4096
#define NROWS (BATCH * NSEQ)  // 8192

__device__ inline ushort f2bf(float f) {
  uint u = __float_as_uint(f);
  u += 0x7fff + ((u >> 16) & 1);  // round-to-nearest-even
  return (ushort)(u >> 16);
}

__device__ inline f32x4 zero4() {
  f32x4 z; z[0] = 0.f; z[1] = 0.f; z[2] = 0.f; z[3] = 0.f; return z;
}

// gelu(x) = x * sigmoid(2u), u = 0.79788456(x + 0.044715 x^3)  (exact identity
// with the tanh form). exp(-2u) = exp2(-2u*log2e).
__device__ inline float gelu_fast(float x) {
  float u2 = 1.5957691216057308f * (x + 0.044715f * x * x * x);  // 2u
  float e = __builtin_amdgcn_exp2f(-1.4426950408889634f * u2);
  return x / (1.0f + e);
}

#define GLDS16(g, l)                                                  \
  __builtin_amdgcn_global_load_lds(                                   \
      (const __attribute__((address_space(1))) void*)(g),             \
      (__attribute__((address_space(3))) void*)(l), 16, 0, 0)

#define WAITVM(n) asm volatile("s_waitcnt vmcnt(" #n ")" ::: "memory")
#define SBAR() asm volatile("s_barrier" ::: "memory")

// ---------------- LayerNorm (fp32 in -> bf16 out) ----------------
__global__ __launch_bounds__(256) void ln_kernel(
    const float* __restrict__ x, const float* __restrict__ sc,
    const float* __restrict__ bi, ushort* __restrict__ out) {
  int row = blockIdx.x;
  int t = threadIdx.x;
  const float4 v = reinterpret_cast<const float4*>(x + (size_t)row * DIM)[t];
  float s = v.x + v.y + v.z + v.w;
  float s2 = v.x * v.x + v.y * v.y + v.z * v.z + v.w * v.w;
#pragma unroll
  for (int off = 32; off >= 1; off >>= 1) {
    s += __shfl_xor(s, off);
    s2 += __shfl_xor(s2, off);
  }
  __shared__ float ps[4], ps2[4];
  int w = t >> 6;
  if ((t & 63) == 0) { ps[w] = s; ps2[w] = s2; }
  __syncthreads();
  s = ps[0] + ps[1] + ps[2] + ps[3];
  s2 = ps2[0] + ps2[1] + ps2[2] + ps2[3];
  float mu = s * (1.0f / DIM);
  float var = s2 * (1.0f / DIM) - mu * mu;
  float rstd = rsqrtf(var + 1e-6f);
  float4 scv = reinterpret_cast<const float4*>(sc)[t];
  float4 biv = reinterpret_cast<const float4*>(bi)[t];
  ushort4 o;
  o.x = f2bf((v.x - mu) * rstd * scv.x + biv.x);
  o.y = f2bf((v.y - mu) * rstd * scv.y + biv.y);
  o.z = f2bf((v.z - mu) * rstd * scv.z + biv.z);
  o.w = f2bf((v.w - mu) * rstd * scv.w + biv.w);
  reinterpret_cast<ushort4*>(out + (size_t)row * DIM)[t] = o;
}

// ------- fused weight transposes: all four fp32 [K][N] -> bf16 [N][K] -------
__global__ __launch_bounds__(256) void wtrans4_kernel(
    const float* __restrict__ w_qkv, ushort* __restrict__ wqkv_t,
    const float* __restrict__ w_proj, ushort* __restrict__ wproj_t,
    const float* __restrict__ w_fc1, ushort* __restrict__ wfc1_t,
    const float* __restrict__ w_fc2, ushort* __restrict__ wfc2_t) {
  int b = blockIdx.x;
  const float* w; ushort* wt; int K, N, bx, by;
  if (b < 3072) {                    // w_qkv: K=1024, N=3072 (96x32 blocks)
    w = w_qkv; wt = wqkv_t; K = 1024; N = 3072; bx = b % 96; by = b / 96;
  } else if (b < 4096) {             // w_proj: K=1024, N=1024 (32x32)
    int i = b - 3072;
    w = w_proj; wt = wproj_t; K = 1024; N = 1024; bx = i % 32; by = i / 32;
  } else if (b < 8192) {             // w_fc1: K=1024, N=4096 (128x32)
    int i = b - 4096;
    w = w_fc1; wt = wfc1_t; K = 1024; N = 4096; bx = i % 128; by = i / 128;
  } else {                           // w_fc2: K=4096, N=1024 (32x128)
    int i = b - 8192;
    w = w_fc2; wt = wfc2_t; K = 4096; N = 1024; bx = i % 32; by = i / 32;
  }
  __shared__ float tile[32][33];
  int n0 = bx * 32, k0 = by * 32;
  int tx = threadIdx.x & 31, ty = threadIdx.x >> 5;
#pragma unroll
  for (int j = 0; j < 4; j++)
    tile[ty + 8 * j][tx] = w[(size_t)(k0 + ty + 8 * j) * N + n0 + tx];
  __syncthreads();
#pragma unroll
  for (int j = 0; j < 4; j++)
    wt[(size_t)(n0 + ty + 8 * j) * K + k0 + tx] = f2bf(tile[tx][ty + 8 * j]);
}

// ---------------- V transpose: qkv v-part [b,n][h,d] -> vT [b,h,d][n] ----------------
__global__ __launch_bounds__(256) void vtrans_kernel(
    const ushort* __restrict__ qkv, ushort* __restrict__ vT) {
  __shared__ ushort Ts[64 * 64];
  int bh = blockIdx.y;
  int b = bh >> 4, h = bh & 15;
  int n0 = blockIdx.x * 64;
  int t = threadIdx.x;
  const ushort* src = qkv + (size_t)b * NSEQ * 3072 + 2048 + h * 64;
#pragma unroll
  for (int i = 0; i < 2; i++) {
    int ci = i * 256 + t;
    int rr = ci >> 3, c = ci & 7;
    short8 v = *reinterpret_cast<const short8*>(src + (size_t)(n0 + rr) * 3072 + c * 8);
    *reinterpret_cast<short8*>(&Ts[rr * 64 + ((c ^ (rr >> 3)) & 7) * 8]) = v;
  }
  __syncthreads();
  ushort* dst = vT + (size_t)bh * 64 * NSEQ;
#pragma unroll
  for (int i = 0; i < 2; i++) {
    int ci = i * 256 + t;
    int dd = ci >> 3, c = ci & 7;
    short8 v;
#pragma unroll
    for (int j = 0; j < 8; j++) {
      int nn = c * 8 + j;
      v[j] = (short)Ts[nn * 64 + (((dd >> 3) ^ (nn >> 3)) & 7) * 8 + (dd & 7)];
    }
    *reinterpret_cast<short8*>(dst + (size_t)dd * NSEQ + n0 + c * 8) = v;
  }
}

// ---------------- GEMM A: 256-tile pipelined (best for qkv/proj/fc2) --------
// 4-deep LDS circular buffer, BK=32, register prefetch 1 tile ahead,
// ONE vmcnt(L)+s_barrier per K-tile.
template <int BN, int EPI, int KK>
__global__ __launch_bounds__(512, 2) void gemm256_kernel(
    const ushort* __restrict__ A, const ushort* __restrict__ Bt,
    const float* __restrict__ bias, const float* __restrict__ res,
    void* __restrict__ outp, int M, int N) {
  constexpr int BM = 256, BK = 32;
  constexpr int WM = (BN == 256) ? 2 : 4;  // waves in M
  constexpr int WN = 8 / WM;               // waves in N
  constexpr int MR = (BM / WM) / 16;       // 8 or 4 frags per wave in M
  constexpr int NR = (BN / WN) / 16;       // 4 frags per wave in N
  constexpr int AR = 2;                    // A staging rounds (128 rows each)
  constexpr int BR = BN / 128;             // B staging rounds
  constexpr int nkt = KK / BK;             // 32 or 128 (even)
  static_assert(BN == 256 || BN == 128, "");
  static_assert(nkt >= 4 && (nkt % 2) == 0, "");

  __shared__ ushort As[4][BM * BK];        // 64 KB
  __shared__ ushort Bs[4][BN * BK];        // 64/32 KB

  int t = threadIdx.x, lane = t & 63, w = t >> 6;
  int wr = w / WN, wc = w % WN;
  int r = lane & 15, g = lane >> 4;

  // XCD-aware block swizzle (all grids here are multiples of 8 blocks)
  int nwg = gridDim.x * gridDim.y;
  int flat = blockIdx.y * gridDim.x + blockIdx.x;
  int swzf = (flat & 7) * (nwg >> 3) + (flat >> 3);
  int bx = swzf % gridDim.x, by = swzf / gridDim.x;
  int m0 = by * BM, n0 = bx * BN;

  const ushort* Ab = A + (size_t)m0 * KK;
  const ushort* Bb = Bt + (size_t)n0 * KK;

  int srow = t >> 2;                                            // 0..127
  int sgc8 = (((t & 3) ^ (srow & 3) ^ ((srow >> 2) & 3)) & 3) * 8;
  int swb = (w << 4) * BK;                                      // wave LDS base
  int sw = ((g ^ (r & 3) ^ ((r >> 2) & 3)) & 3) * 8;            // read swizzle

  auto stageAB = [&](int kt2) {
    ushort* as = &As[kt2 & 3][0];
    ushort* bs = &Bs[kt2 & 3][0];
    int ko = kt2 * BK;
#pragma unroll
    for (int p = 0; p < AR; p++)
      GLDS16(Ab + (size_t)(p * 128 + srow) * KK + ko + sgc8,
             as + p * 128 * BK + swb);
#pragma unroll
    for (int p = 0; p < BR; p++)
      GLDS16(Bb + (size_t)(p * 128 + srow) * KK + ko + sgc8,
             bs + p * 128 * BK + swb);
  };

  auto ldfrags = [&](int kt2, short8 (&fa_)[MR], short8 (&fb_)[NR]) {
    const ushort* as = &As[kt2 & 3][0];
    const ushort* bs = &Bs[kt2 & 3][0];
#pragma unroll
    for (int mi = 0; mi < MR; mi++)
      fa_[mi] = *reinterpret_cast<const short8*>(
          &as[(wr * (BM / WM) + mi * 16 + r) * BK + sw]);
#pragma unroll
    for (int ni = 0; ni < NR; ni++)
      fb_[ni] = *reinterpret_cast<const short8*>(
          &bs[(wc * (BN / WN) + ni * 16 + r) * BK + sw]);
  };

  f32x4 acc[MR][NR];
#pragma unroll
  for (int mi = 0; mi < MR; mi++)
#pragma unroll
    for (int ni = 0; ni < NR; ni++) acc[mi][ni] = zero4();

  auto body = [&](int kt, short8 (&ca)[MR], short8 (&cb)[NR],
                  short8 (&na)[MR], short8 (&nb)[NR]) {
    if (kt + 1 < nkt) ldfrags(kt + 1, na, nb);   // overlaps MFMAs below
    if (kt + 3 < nkt) stageAB(kt + 3);           // HBM -> buf[kt-1]
    __builtin_amdgcn_s_setprio(1);
#pragma unroll
    for (int mi = 0; mi < MR; mi++)
#pragma unroll
      for (int ni = 0; ni < NR; ni++)
        acc[mi][ni] = __builtin_amdgcn_mfma_f32_16x16x32_bf16(
            ca[mi], cb[ni], acc[mi][ni], 0, 0, 0);
    __builtin_amdgcn_s_setprio(0);
    if (kt + 3 < nkt) {
      if constexpr (BN == 256) WAITVM(4); else WAITVM(3);
      SBAR();
    } else if (kt + 2 < nkt) {
      WAITVM(0);
      SBAR();
    }  // else: last-2 tiles, no future reads/stages -> no sync needed
  };

  // prologue: 3 tiles in flight; wait stage(0),(1) done (stage(2) in flight)
  stageAB(0); stageAB(1); stageAB(2);
  if constexpr (BN == 256) WAITVM(4); else WAITVM(3);
  SBAR();

  short8 fa[2][MR], fb[2][NR];
  ldfrags(0, fa[0], fb[0]);
#pragma unroll 1
  for (int k2 = 0; k2 < nkt / 2; k2++) {
    body(2 * k2 + 0, fa[0], fb[0], fa[1], fb[1]);
    body(2 * k2 + 1, fa[1], fb[1], fa[0], fb[0]);
  }

  int rg = g * 4;
#pragma unroll
  for (int mi = 0; mi < MR; mi++) {
#pragma unroll
    for (int ni = 0; ni < NR; ni++) {
      int row = m0 + wr * (BM / WM) + mi * 16 + rg;
      int col = n0 + wc * (BN / WN) + ni * 16 + r;
      float bv = bias[col];
#pragma unroll
      for (int j = 0; j < 4; j++) {
        float v = acc[mi][ni][j] + bv;
        if (EPI == 1) v = gelu_fast(v);
        if (EPI == 2) {
          reinterpret_cast<float*>(outp)[(size_t)(row + j) * N + col] =
              v + res[(size_t)(row + j) * N + col];
        } else {
          reinterpret_cast<ushort*>(outp)[(size_t)(row + j) * N + col] = f2bf(v);
        }
      }
    }
  }
}

// ---------------- GEMM B: m97 128x128 replica (fc1 113.5 us, R3/R6-exact) ---
// 128x128 tile, BK=32, 256 threads (2x2 waves, 64x64 out each, 4x4 frags),
// 2-deep LDS double-buffer (32 KB), global_load_lds width-16 staging,
// plain __syncthreads per K-tile, __launch_bounds__(256,3).
template <int EPI>
__global__ __launch_bounds__(256, 3) void gemm128_kernel(
    const ushort* __restrict__ A, const ushort* __restrict__ Bt,
    const float* __restrict__ bias, const float* __restrict__ res,
    void* __restrict__ outp, int M, int N, int K) {
  constexpr int BM = 128, BN = 128, BK = 32;

  __shared__ ushort As[2][BM * BK];  // 8 KB each
  __shared__ ushort Bs[2][BN * BK];

  int t = threadIdx.x, lane = t & 63, w = t >> 6;
  int wr = w >> 1, wc = w & 1;
  int r = lane & 15, g = lane >> 4;

  // XCD-aware block swizzle (all grids here are multiples of 8 blocks)
  int nwg = gridDim.x * gridDim.y;
  int flat = blockIdx.y * gridDim.x + blockIdx.x;
  int swzf = (flat & 7) * (nwg >> 3) + (flat >> 3);
  int bx = swzf % gridDim.x, by = swzf / gridDim.x;
  int m0 = by * BM, n0 = bx * BN;

  const ushort* Ab = A + (size_t)m0 * K;
  const ushort* Bb = Bt + (size_t)n0 * K;

  int srow = t >> 2;  // 0..63
  int sgc8 = (((t & 3) ^ (srow & 3) ^ ((srow >> 2) & 3)) & 3) * 8;
  int swb = (t >> 6) * 16 * BK;  // wave LDS base (rows w*16.., 1 KB per wave)
  int sw = ((g ^ (r & 3) ^ ((r >> 2) & 3)) & 3) * 8;  // read-side swizzle

  f32x4 acc[4][4];
#pragma unroll
  for (int mi = 0; mi < 4; mi++)
#pragma unroll
    for (int ni = 0; ni < 4; ni++) acc[mi][ni] = zero4();

  int nkt = K / BK;
  // prologue: stage tile 0 into buf 0
#pragma unroll
  for (int p = 0; p < 2; p++) {
    GLDS16(Ab + (size_t)(p * 64 + srow) * K + sgc8, &As[0][(p * 64) * BK + swb]);
    GLDS16(Bb + (size_t)(p * 64 + srow) * K + sgc8, &Bs[0][(p * 64) * BK + swb]);
  }
  __syncthreads();

  int cur = 0;
  for (int kt = 0; kt < nkt; kt++) {
    if (kt + 1 < nkt) {  // stage next tile; drained by the __syncthreads below
      int ko = (kt + 1) * BK;
#pragma unroll
      for (int p = 0; p < 2; p++) {
        GLDS16(Ab + (size_t)(p * 64 + srow) * K + ko + sgc8,
               &As[cur ^ 1][(p * 64) * BK + swb]);
        GLDS16(Bb + (size_t)(p * 64 + srow) * K + ko + sgc8,
               &Bs[cur ^ 1][(p * 64) * BK + swb]);
      }
    }
    short8 a[4], b[4];
#pragma unroll
    for (int mi = 0; mi < 4; mi++)
      a[mi] = *reinterpret_cast<const short8*>(
          &As[cur][(wr * 64 + mi * 16 + r) * BK + sw]);
#pragma unroll
    for (int ni = 0; ni < 4; ni++)
      b[ni] = *reinterpret_cast<const short8*>(
          &Bs[cur][(wc * 64 + ni * 16 + r) * BK + sw]);
#pragma unroll
    for (int mi = 0; mi < 4; mi++)
#pragma unroll
      for (int ni = 0; ni < 4; ni++)
        acc[mi][ni] = __builtin_amdgcn_mfma_f32_16x16x32_bf16(
            a[mi], b[ni], acc[mi][ni], 0, 0, 0);
    __syncthreads();  // drains GLDS (vmcnt 0) + all waves done with buf[cur]
    cur ^= 1;
  }

  int rg = g * 4;
#pragma unroll
  for (int mi = 0; mi < 4; mi++) {
#pragma unroll
    for (int ni = 0; ni < 4; ni++) {
      int row = m0 + wr * 64 + mi * 16 + rg;
      int col = n0 + wc * 64 + ni * 16 + r;
      float bv = bias[col];
#pragma unroll
      for (int j = 0; j < 4; j++) {
        float v = acc[mi][ni][j] + bv;
        if (EPI == 1) v = gelu_fast(v);
        if (EPI == 2) {
          reinterpret_cast<float*>(outp)[(size_t)(row + j) * N + col] =
              v + res[(size_t)(row + j) * N + col];
        } else {
          reinterpret_cast<ushort*>(outp)[(size_t)(row + j) * N + col] = f2bf(v);
        }
      }
    }
  }
}

// ---------------- flash attention (no-max-subtract softmax) ----------------
// REVERTED to LDS-staged K/V (R9's direct-read version was 5x slower: FETCH
// 147MB vs 17MB -- 4 waves x 16 q-blocks redundant global reads thrash L2;
// staging IS the reuse mechanism here). NEW vs R8: T14 async-STAGE split
// (+17% measured on attn, m214v27) -- global loads for tile kt+1 are issued
// right after tile kt's LDS writes, so HBM/L2 latency hides under the
// QK^T+softmax+PV compute; the ds_write at kt+1 carries the compiler's
// automatic vmcnt wait. Single kreg/vreg set (regs consumed by LDS write
// before reload). Barrier structure unchanged.
#define SM_SCALE_L2E 0.18033688f   // 0.125 * log2(e)
#define SM_BIAS_L2E 11.54156036f   // 8 * log2(e)
__global__ __launch_bounds__(256) void attn_kernel(
    const ushort* __restrict__ qkv, const ushort* __restrict__ vT,
    ushort* __restrict__ o) {
  __shared__ ushort Kt[64 * 72];
  __shared__ ushort Vt[64 * 72];
  __shared__ ushort Pl[4][16 * 72];
  int q0 = blockIdx.x * 64, h = blockIdx.y, b = blockIdx.z;
  int t = threadIdx.x, lane = t & 63, w = t >> 6;
  int r = lane & 15, g = lane >> 4;
  const ushort* base = qkv + (size_t)b * NSEQ * 3072 + h * 64;
  const ushort* vbase = vT + (size_t)(b * HEADS + h) * 64 * NSEQ;

  short8 qf[2];
  {
    const ushort* qrow = base + (size_t)(q0 + w * 16 + r) * 3072;
    qf[0] = *reinterpret_cast<const short8*>(qrow + g * 8);
    qf[1] = *reinterpret_cast<const short8*>(qrow + 32 + g * 8);
  }

  float l[4] = {0.f, 0.f, 0.f, 0.f};
  f32x4 oacc[4];
#pragma unroll
  for (int db = 0; db < 4; db++) oacc[db] = zero4();

  int srw = t >> 3, sc8 = (t & 7) * 8;
  short8 kreg[2], vreg[2];
  // preload tile 0 into registers
#pragma unroll
  for (int i = 0; i < 2; i++) {
    int rw = srw + i * 32;
    kreg[i] = *reinterpret_cast<const short8*>(base + 1024 + (size_t)rw * 3072 + sc8);
    vreg[i] = *reinterpret_cast<const short8*>(vbase + (size_t)rw * NSEQ + sc8);
  }

  for (int kt = 0; kt < NSEQ / 64; kt++) {
    __syncthreads();  // all waves done reading Kt/Vt from previous tile
#pragma unroll
    for (int i = 0; i < 2; i++) {  // auto s_waitcnt vmcnt for kreg/vreg deps
      int rw = srw + i * 32;
      *reinterpret_cast<short8*>(&Kt[rw * 72 + sc8]) = kreg[i];
      *reinterpret_cast<short8*>(&Vt[rw * 72 + sc8]) = vreg[i];
    }
    __syncthreads();
    if (kt + 1 < NSEQ / 64) {  // issue next tile's loads; hide under compute
      int k0n = (kt + 1) * 64;
#pragma unroll
      for (int i = 0; i < 2; i++) {
        int rw = srw + i * 32;
        kreg[i] = *reinterpret_cast<const short8*>(
            base + 1024 + (size_t)(k0n + rw) * 3072 + sc8);
        vreg[i] = *reinterpret_cast<const short8*>(
            vbase + (size_t)rw * NSEQ + k0n + sc8);
      }
    }

#pragma unroll
    for (int kb = 0; kb < 4; kb++) {
      short8 kf0 = *reinterpret_cast<const short8*>(&Kt[(kb * 16 + r) * 72 + g * 8]);
      short8 kf1 = *reinterpret_cast<const short8*>(&Kt[(kb * 16 + r) * 72 + 32 + g * 8]);
      f32x4 z = zero4();
      z = __builtin_amdgcn_mfma_f32_16x16x32_bf16(qf[0], kf0, z, 0, 0, 0);
      z = __builtin_amdgcn_mfma_f32_16x16x32_bf16(qf[1], kf1, z, 0, 0, 0);
#pragma unroll
      for (int j = 0; j < 4; j++) {
        float p = __builtin_amdgcn_exp2f(fmaf(z[j], SM_SCALE_L2E, -SM_BIAS_L2E));
        l[j] += p;
        Pl[w][(g * 4 + j) * 72 + kb * 16 + r] = (ushort)(__float_as_uint(p) >> 16);
      }
    }

#pragma unroll
    for (int ks = 0; ks < 2; ks++) {
      short8 pa = *reinterpret_cast<const short8*>(&Pl[w][r * 72 + ks * 32 + g * 8]);
#pragma unroll
      for (int db = 0; db < 4; db++) {
        short8 vb = *reinterpret_cast<const short8*>(&Vt[(db * 16 + r) * 72 + ks * 32 + g * 8]);
        oacc[db] = __builtin_amdgcn_mfma_f32_16x16x32_bf16(pa, vb, oacc[db], 0, 0, 0);
      }
    }
  }

#pragma unroll
  for (int j = 0; j < 4; j++) {
#pragma unroll
    for (int off = 8; off >= 1; off >>= 1) l[j] += __shfl_xor(l[j], off);
    l[j] = 1.0f / l[j];
  }

#pragma unroll
  for (int db = 0; db < 4; db++)
#pragma unroll
    for (int j = 0; j < 4; j++) {
      size_t row = (size_t)b * NSEQ + q0 + w * 16 + g * 4 + j;
      int col = h * 64 + db * 16 + r;
      o[row * DIM + col] = f2bf(oacc[db][j] * l[j]);
    }
}

// ---------------- driver ----------------
extern "C" void kernel_launch(void* const* d_in, const int* in_sizes, int n_in,
                              void* d_out, int out_size, void* d_ws, size_t ws_size,
                              hipStream_t stream) {
  const float* x      = (const float*)d_in[0];
  const float* w_qkv  = (const float*)d_in[1];
  const float* b_qkv  = (const float*)d_in[2];
  const float* w_proj = (const float*)d_in[3];
  const float* b_proj = (const float*)d_in[4];
  const float* ln1s   = (const float*)d_in[5];
  const float* ln1b   = (const float*)d_in[6];
  const float* ln2s   = (const float*)d_in[7];
  const float* ln2b   = (const float*)d_in[8];
  const float* w_fc1  = (const float*)d_in[9];
  const float* b_fc1  = (const float*)d_in[10];
  const float* w_fc2  = (const float*)d_in[11];
  const float* b_fc2  = (const float*)d_in[12];
  float* out = (float*)d_out;

  char* ws = (char*)d_ws;
  ushort* wqkv_t  = (ushort*)(ws);               // [3072][1024] bf16, 6 MB
  ushort* wproj_t = (ushort*)(ws + 6291456);     // [1024][1024], 2 MB
  ushort* wfc1_t  = (ushort*)(ws + 8388608);     // [4096][1024], 8 MB
  ushort* wfc2_t  = (ushort*)(ws + 16777216);    // [1024][4096], 8 MB
  ushort* hbuf    = (ushort*)(ws + 25165824);    // [8192][1024] bf16, 16 MB
  float*  x1      = (float*)(ws + 41943040);     // [8192][1024] f32, 32 MB
  ushort* vTb     = (ushort*)(ws + 41943040);    // [128][64][1024] bf16, 16 MB (dead before x1)
  ushort* qkv     = (ushort*)(ws + 75497472);    // [8192][3072] bf16, 48 MB
  ushort* obuf    = (ushort*)(ws + 125829120);   // [8192][1024] bf16, 16 MB
  ushort* fc1a    = qkv;                         // [8192][4096] bf16, 64 MB

  wtrans4_kernel<<<12288, 256, 0, stream>>>(
      w_qkv, wqkv_t, w_proj, wproj_t, w_fc1, wfc1_t, w_fc2, wfc2_t);

  // attention branch
  ln_kernel<<<NROWS, 256, 0, stream>>>(x, ln1s, ln1b, hbuf);
  gemm256_kernel<128, 0, 1024><<<dim3(3072 / 128, NROWS / 256), 512, 0, stream>>>(
      hbuf, wqkv_t, b_qkv, nullptr, qkv, NROWS, 3072);
  vtrans_kernel<<<dim3(NSEQ / 64, BATCH * HEADS), 256, 0, stream>>>(qkv, vTb);
  attn_kernel<<<dim3(NSEQ / 64, HEADS, BATCH), 256, 0, stream>>>(qkv, vTb, obuf);
  gemm256_kernel<128, 2, 1024><<<dim3(1024 / 128, NROWS / 256), 512, 0, stream>>>(
      obuf, wproj_t, b_proj, x, x1, NROWS, 1024);

  // mlp branch
  ln_kernel<<<NROWS, 256, 0, stream>>>(x1, ln2s, ln2b, hbuf);
  gemm128_kernel<1><<<dim3(4096 / 128, NROWS / 128), 256, 0, stream>>>(
      hbuf, wfc1_t, b_fc1, nullptr, fc1a, NROWS, 4096, 1024);
  gemm256_kernel<128, 2, 4096><<<dim3(1024 / 128, NROWS / 256), 512, 0, stream>>>(
      fc1a, wfc2_t, b_fc2, x1, out, NROWS, 1024);
}